// Round 10
// baseline (616.557 us; speedup 1.0000x reference)
//
#include <hip/hip_runtime.h>
#include <math.h>

// ---------------------------------------------------------------------------
// CapsNet forward on MI355X.
// R9b: (R9 with ext-vector fix for nontemporal builtin)
//  conv2 merged tri-term kst loop: stage A_hi+A_lo slabs together (56.6KB,
//  2 blocks/CU), 108 MFMAs/kst cover for fully-prefetched cbh+cbl; grid
//  512 8-way split (XCD==ks, one dispatch round, 74MB atomics);
//  nontemporal x staging so the 105MB x stream stops evicting the 2.75MB
//  L2-resident weight slice (R8 FETCH rose: x-stream eviction, not
//  capacity). caps_k -> single-wave 64-thr blocks.
// ---------------------------------------------------------------------------

typedef float floatx4 __attribute__((ext_vector_type(4)));
typedef __bf16 bf16x8 __attribute__((ext_vector_type(8)));
typedef unsigned uintx4 __attribute__((ext_vector_type(4)));

#define XHI_OFF 0u
#define XLO_OFF 52428800u
#define WHI_OFF 104857600u          // 84*32*256*8 shorts = 11010048 B
#define WLO_OFF 115867648u
#define Y2_OFF  126877696u
#define VP_OFF  136314880u
#define Y2_BYTES 9437184u

// slab geometry (shorts): iy stride 88, img stride 1760, parity offset 7072
#define SL_IY   88
#define SL_IMG  1760
#define SL_PAR  7072
#define SL_TOT  14144

__device__ __forceinline__ void bf16split(float v, short& hs, short& ls) {
  unsigned u = __builtin_bit_cast(unsigned, v);
  unsigned r = (u + 0x7FFFu + ((u >> 16) & 1u)) & 0xFFFF0000u;
  hs = (short)(r >> 16);
  float lo = v - __builtin_bit_cast(float, r);
  unsigned u2 = __builtin_bit_cast(unsigned, lo);
  unsigned r2 = u2 + 0x7FFFu + ((u2 >> 16) & 1u);
  ls = (short)(r2 >> 16);
}

// ============================ conv1: 9x9 s1 + ReLU ==========================
// Emits x_hi/x_lo bf16 in [b][pos(400)][ic(256)] layout (GEMM-A friendly).
__global__ __launch_bounds__(320) void conv1_k(
    const float* __restrict__ inp, const float* __restrict__ W1,
    const float* __restrict__ b1, short* __restrict__ xhi,
    short* __restrict__ xlo) {
  __shared__ __align__(16) float img[784];
  __shared__ float wl[81 * 34];
  const int blk = blockIdx.x;
  const int b = blk >> 3;
  const int cbase = (blk & 7) * 32;
  const int t = threadIdx.x;

  const float4* src = (const float4*)(inp + b * 784);
  for (int idx = t; idx < 196; idx += 320) ((float4*)img)[idx] = src[idx];
  for (int idx = t; idx < 2592; idx += 320) {
    int c = idx / 81, tap = idx - c * 81;
    wl[tap * 34 + c] = W1[(cbase + c) * 81 + tap];
  }
  __syncthreads();

  const int oy = t >> 4;
  const int ct = t & 15;
  const int c0 = cbase + ct * 2;
  const float bias0 = b1[c0], bias1 = b1[c0 + 1];
  float acc0[20], acc1[20];
#pragma unroll
  for (int ox = 0; ox < 20; ox++) { acc0[ox] = bias0; acc1[ox] = bias1; }

#pragma unroll 1
  for (int i = 0; i < 9; i++) {
    float wr0[9], wr1[9];
#pragma unroll
    for (int j = 0; j < 9; j++) {
      float2 wv = *(const float2*)&wl[(i * 9 + j) * 34 + ct * 2];
      wr0[j] = wv.x; wr1[j] = wv.y;
    }
    float xr[28];
    const float4* rp = (const float4*)&img[(oy + i) * 28];
#pragma unroll
    for (int k = 0; k < 7; k++) {
      float4 v = rp[k];
      xr[4 * k] = v.x; xr[4 * k + 1] = v.y; xr[4 * k + 2] = v.z; xr[4 * k + 3] = v.w;
    }
#pragma unroll
    for (int j = 0; j < 9; j++)
#pragma unroll
      for (int ox = 0; ox < 20; ox++) {
        acc0[ox] = fmaf(xr[ox + j], wr0[j], acc0[ox]);
        acc1[ox] = fmaf(xr[ox + j], wr1[j], acc1[ox]);
      }
  }
  const long pbase = (long)(b * 400 + oy * 20) * 256 + c0;
#pragma unroll
  for (int ox = 0; ox < 20; ox++) {
    float v0 = fmaxf(acc0[ox], 0.f), v1 = fmaxf(acc1[ox], 0.f);
    short h0, l0, h1, l1;
    bf16split(v0, h0, l0);
    bf16split(v1, h1, l1);
    long a = pbase + (long)ox * 256;
    *(short2*)&xhi[a] = make_short2(h0, h1);
    *(short2*)&xlo[a] = make_short2(l0, l1);
  }
}

// ======= W2 transform: fp32 [oc][ic][81] -> bf16 hi/lo, 84-tap padded =======
// out layout: [tap(84)][icg(32)][oc(256)][ics(8)]; taps 81..83 zero.
__global__ __launch_bounds__(256) void wtrans_k(
    const float* __restrict__ W2, short* __restrict__ whi,
    short* __restrict__ wlo) {
  const int idx = blockIdx.x * 256 + threadIdx.x;  // < 5505024
  const int ics = idx & 7;
  const int oc = (idx >> 3) & 255;
  const int icg = (idx >> 11) & 31;
  const int tap = idx >> 16;
  short h = 0, l = 0;
  if (tap < 81) {
    const int ic = icg * 8 + ics;
    bf16split(W2[(oc * 256 + ic) * 81 + tap], h, l);
  }
  whi[idx] = h;
  wlo[idx] = l;
}

// ================= conv2: MFMA bf16-split implicit GEMM =====================
// grid 512 (one residency round): ks = blk&7 == XCD (2.75MB weight slice,
// L2-resident), mb = blk>>3 (4 images). Block M144 x N256; 4 waves x (9m,4n).
// Merged tri-term kst loop: A_hi + A_lo slabs staged together; per kst
// 108 MFMAs cover the 8 prefetched B-frag loads (cbh+cbl, 1-kst ahead).
__global__ __launch_bounds__(256, 2) void conv2_k(
    const short* __restrict__ xhi, const short* __restrict__ xlo,
    const short* __restrict__ whi, const short* __restrict__ wlo,
    float* __restrict__ y2) {
  __shared__ __align__(16) short slabH[SL_TOT];   // 28.3 KB
  __shared__ __align__(16) short slabL[SL_TOT];   // 28.3 KB

  const int blk = blockIdx.x;
  const int ks = blk & 7;
  const int mb = blk >> 3;
  const int b0 = mb * 4;
  const int t = threadIdx.x;
  const int lane = t & 63;
  const int q = lane >> 4;
  const int ln16 = lane & 15;
  const int wv = t >> 6;

  int combo[9];
#pragma unroll
  for (int mt = 0; mt < 9; mt++) {
    int row = mt * 16 + ln16;
    int im = row / 36;
    int pos = row - im * 36;
    int oy = pos / 6, ox = pos - oy * 6;
    combo[mt] = im * SL_IMG + oy * (2 * SL_IY) + ox * 8;
  }

  floatx4 acc[9][4];
#pragma unroll
  for (int mt = 0; mt < 9; mt++)
#pragma unroll
    for (int nt = 0; nt < 4; nt++) acc[mt][nt] = (floatx4)0.f;

#pragma unroll 1
  for (int icg = 0; icg < 4; icg++) {
    const int icgG = ks * 4 + icg;
    const long icoff = (long)icgG * 8;
    // per-lane weight base (shorts): ((tap*32 + icgG)*256 + oc)*8
    const long wb0 = ((long)icgG * 256 + wv * 64 + ln16) * 8 + (long)q * 65536;

    // stage A_hi + A_lo slabs (nontemporal: don't evict weights from L2)
    __syncthreads();
    for (int idx = t; idx < 1600; idx += 256) {
      int im = idx / 400, p = idx - im * 400;
      int iy = p / 20, ix = p - iy * 20;
      int dst = (ix & 1) * SL_PAR + im * SL_IMG + iy * SL_IY + (ix >> 1) * 8;
      const long src = ((long)(b0 + im) * 400 + p) * 256 + icoff;
      uintx4 vh = __builtin_nontemporal_load((const uintx4*)&xhi[src]);
      uintx4 vl = __builtin_nontemporal_load((const uintx4*)&xlo[src]);
      *(uintx4*)&slabH[dst] = vh;
      *(uintx4*)&slabL[dst] = vl;
    }
    __syncthreads();

    bf16x8 cbh[4], cbl[4];
#pragma unroll
    for (int nt = 0; nt < 4; nt++) {
      cbh[nt] = *(const bf16x8*)&whi[wb0 + nt * 128];
      cbl[nt] = *(const bf16x8*)&wlo[wb0 + nt * 128];
    }
#pragma unroll 1
    for (int kst = 0; kst < 21; kst++) {
      const int t0n = (kst < 20) ? (kst + 1) * 4 : 80;
      bf16x8 nbh[4], nbl[4];
#pragma unroll
      for (int nt = 0; nt < 4; nt++) {
        nbh[nt] = *(const bf16x8*)&whi[wb0 + (long)t0n * 65536 + nt * 128];
        nbl[nt] = *(const bf16x8*)&wlo[wb0 + (long)t0n * 65536 + nt * 128];
      }
      const int tap = kst * 4 + q;
      const int i = tap / 9, j = tap - i * 9;
      const int aoff = (j & 1) * SL_PAR + i * SL_IY + (j >> 1) * 8;
#pragma unroll
      for (int bb = 0; bb < 3; bb++) {
        bf16x8 ah[3], al[3];
#pragma unroll
        for (int m3 = 0; m3 < 3; m3++) {
          ah[m3] = *(const bf16x8*)&slabH[aoff + combo[bb * 3 + m3]];
          al[m3] = *(const bf16x8*)&slabL[aoff + combo[bb * 3 + m3]];
        }
        // three terms, each 12 independent MFMAs (dep-acc distance 12)
#pragma unroll
        for (int nt = 0; nt < 4; nt++)
#pragma unroll
          for (int m3 = 0; m3 < 3; m3++)
            acc[bb * 3 + m3][nt] = __builtin_amdgcn_mfma_f32_16x16x32_bf16(
                ah[m3], cbh[nt], acc[bb * 3 + m3][nt], 0, 0, 0);
#pragma unroll
        for (int nt = 0; nt < 4; nt++)
#pragma unroll
          for (int m3 = 0; m3 < 3; m3++)
            acc[bb * 3 + m3][nt] = __builtin_amdgcn_mfma_f32_16x16x32_bf16(
                ah[m3], cbl[nt], acc[bb * 3 + m3][nt], 0, 0, 0);
#pragma unroll
        for (int nt = 0; nt < 4; nt++)
#pragma unroll
          for (int m3 = 0; m3 < 3; m3++)
            acc[bb * 3 + m3][nt] = __builtin_amdgcn_mfma_f32_16x16x32_bf16(
                al[m3], cbh[nt], acc[bb * 3 + m3][nt], 0, 0, 0);
      }
#pragma unroll
      for (int nt = 0; nt < 4; nt++) { cbh[nt] = nbh[nt]; cbl[nt] = nbl[nt]; }
    }
  }

  // epilogue: C/D layout col(n)=lane&15, row(m)=q*4+r; atomic over 8 ic-splits
#pragma unroll
  for (int mt = 0; mt < 9; mt++)
#pragma unroll
    for (int nt = 0; nt < 4; nt++) {
      int oc = wv * 64 + nt * 16 + ln16;
      int rowb = mb * 144 + mt * 16 + q * 4;
#pragma unroll
      for (int r = 0; r < 4; r++)
        atomicAdd(&y2[(long)(rowb + r) * 256 + oc], acc[mt][nt][r]);
    }
}

// ================= primary caps squash + predictions + routing ==============
// grid 8192, single-wave blocks (64 thr): near-free barriers, less idle-lane
// waste in t<36 / t<160 phases. g = blk&31 keeps Wcaps slice L2-hot per XCD.
__global__ __launch_bounds__(64) void caps_k(
    const float* __restrict__ y2, const float* __restrict__ b2,
    const float* __restrict__ Wcaps, const float* __restrict__ b_route,
    float* __restrict__ vpart) {
  __shared__ float u[288];
  __shared__ float usc[36];
  __shared__ float up[5760];
  __shared__ float bl[360];
  __shared__ float cl[360];
  __shared__ float sv[160];
  __shared__ float vv[160];
  __shared__ float scale[10];
  const int blk = blockIdx.x;
  const int g = blk & 31, b = blk >> 5;
  const int t = threadIdx.x;

  for (int idx = t; idx < 288; idx += 64) {
    int s = idx >> 3, d = idx & 7;
    u[idx] = y2[((long)b * 36 + s) * 256 + g * 8 + d] + b2[g * 8 + d];
  }
  for (int idx = t; idx < 360; idx += 64) bl[idx] = b_route[g * 360 + idx];
  __syncthreads();
  if (t < 36) {
    float l2 = 0.f;
#pragma unroll
    for (int d = 0; d < 8; d++) { float v = u[t * 8 + d]; l2 = fmaf(v, v, l2); }
    float l = sqrtf(l2);
    usc[t] = (l2 / (1.f + l2)) / (l + 1e-8f);
  }
  __syncthreads();
  for (int idx = t; idx < 288; idx += 64) u[idx] *= usc[idx >> 3];
  __syncthreads();
  for (int idx = t; idx < 5760; idx += 64) {
    int s = idx / 160, k = idx - s * 160;
    const float* wp = Wcaps + (g * 36 + s) * 8 * 160 + k;
    float a = 0.f;
#pragma unroll
    for (int d = 0; d < 8; d++) a = fmaf(u[s * 8 + d], wp[d * 160], a);
    up[idx] = a;
  }
  __syncthreads();

  for (int r = 0; r < 3; r++) {
    if (t < 36) {
      float m = bl[t * 10];
#pragma unroll
      for (int oc = 1; oc < 10; oc++) m = fmaxf(m, bl[t * 10 + oc]);
      float e[10]; float sum = 0.f;
#pragma unroll
      for (int oc = 0; oc < 10; oc++) { e[oc] = expf(bl[t * 10 + oc] - m); sum += e[oc]; }
      float inv = 1.f / sum;
#pragma unroll
      for (int oc = 0; oc < 10; oc++) cl[t * 10 + oc] = e[oc] * inv;
    }
    __syncthreads();
    for (int idx = t; idx < 160; idx += 64) {
      const int oc = idx >> 4;
      float a = 0.f;
#pragma unroll 4
      for (int s = 0; s < 36; s++) a = fmaf(cl[s * 10 + oc], up[s * 160 + idx], a);
      sv[idx] = a;
    }
    __syncthreads();
    if (t < 10) {
      float l2 = 0.f;
#pragma unroll
      for (int od = 0; od < 16; od++) { float v = sv[t * 16 + od]; l2 = fmaf(v, v, l2); }
      scale[t] = (l2 / (1.f + l2)) / (sqrtf(l2) + 1e-8f);
    }
    __syncthreads();
    for (int idx = t; idx < 160; idx += 64) vv[idx] = sv[idx] * scale[idx >> 4];
    __syncthreads();
    if (r < 2) {
      for (int idx = t; idx < 360; idx += 64) {
        int s = idx / 10, oc = idx - s * 10;
        float a = 0.f;
#pragma unroll
        for (int od = 0; od < 16; od++)
          a = fmaf(up[s * 160 + oc * 16 + od], vv[oc * 16 + od], a);
        bl[idx] += a;
      }
      __syncthreads();
    }
  }
  for (int idx = t; idx < 160; idx += 64) vpart[(b * 32 + g) * 160 + idx] = vv[idx];
}

// ================== final: sum over groups + probs ==========================
__global__ __launch_bounds__(192) void final_k(
    const float* __restrict__ vpart, float* __restrict__ out) {
  __shared__ float v[160];
  const int b = blockIdx.x, t = threadIdx.x;
  if (t < 160) {
    float a = 0.f;
#pragma unroll 4
    for (int g = 0; g < 32; g++) a += vpart[(b * 32 + g) * 160 + t];
    v[t] = a;
    out[b * 160 + t] = a;
  }
  __syncthreads();
  if (t < 10) {
    float l2 = 0.f;
#pragma unroll
    for (int od = 0; od < 16; od++) { float x = v[t * 16 + od]; l2 = fmaf(x, x, l2); }
    out[40960 + b * 10 + t] = sqrtf(l2);
  }
}

// ===========================================================================
extern "C" void kernel_launch(void* const* d_in, const int* in_sizes, int n_in,
                              void* d_out, int out_size, void* d_ws, size_t ws_size,
                              hipStream_t stream) {
  const float* inp     = (const float*)d_in[0];
  const float* W1      = (const float*)d_in[1];
  const float* b1      = (const float*)d_in[2];
  const float* W2      = (const float*)d_in[3];
  const float* b2      = (const float*)d_in[4];
  const float* Wcaps   = (const float*)d_in[5];
  const float* b_route = (const float*)d_in[6];
  float* out = (float*)d_out;
  char* ws = (char*)d_ws;

  short* xhi = (short*)(ws + XHI_OFF);
  short* xlo = (short*)(ws + XLO_OFF);
  short* whi = (short*)(ws + WHI_OFF);
  short* wlo = (short*)(ws + WLO_OFF);
  float* y2  = (float*)(ws + Y2_OFF);
  float* vp  = (float*)(ws + VP_OFF);

  (void)hipMemsetAsync(y2, 0, Y2_BYTES, stream);
  conv1_k <<<2048, 320, 0, stream>>>(inp, W1, b1, xhi, xlo);
  wtrans_k<<<21504, 256, 0, stream>>>(W2, whi, wlo);
  conv2_k <<<512, 256, 0, stream>>>(xhi, xlo, whi, wlo, y2);
  caps_k  <<<8192, 64, 0, stream>>>(y2, b2, Wcaps, b_route, vp);
  final_k <<<256, 192, 0, stream>>>(vp, out);
}

// Round 11
// 598.352 us; speedup vs baseline: 1.0304x; 1.0304x over previous
//
#include <hip/hip_runtime.h>
#include <math.h>

// ---------------------------------------------------------------------------
// CapsNet forward on MI355X.
// R11: caps_k reverted to 256-thr (R10's 64-thr was LDS-occupancy-bound:
//      5 waves/CU). conv2: ping-pong kst unroll (no cb=nb v_movs) +
//      pointer-bump weight addressing (weights padded to 88 taps, per-load
//      imm offsets) to cut ~60 dead VALU/kst.
// ---------------------------------------------------------------------------

typedef float floatx4 __attribute__((ext_vector_type(4)));
typedef __bf16 bf16x8 __attribute__((ext_vector_type(8)));
typedef unsigned uintx4 __attribute__((ext_vector_type(4)));

#define XHI_OFF 0u
#define XLO_OFF 52428800u
#define WHI_OFF 104857600u          // 88*32*256*8 shorts = 11534336 B
#define WLO_OFF 116391936u
#define Y2_OFF  127926272u
#define VP_OFF  137363456u
#define Y2_BYTES 9437184u

// slab geometry (shorts): iy stride 88, img stride 1760, parity offset 7072
#define SL_IY   88
#define SL_IMG  1760
#define SL_PAR  7072
#define SL_TOT  14144

#define TAPSTRIDE 65536            // shorts per tap in w layout
#define KSTSTRIDE 262144           // 4 taps

__device__ __forceinline__ void bf16split(float v, short& hs, short& ls) {
  unsigned u = __builtin_bit_cast(unsigned, v);
  unsigned r = (u + 0x7FFFu + ((u >> 16) & 1u)) & 0xFFFF0000u;
  hs = (short)(r >> 16);
  float lo = v - __builtin_bit_cast(float, r);
  unsigned u2 = __builtin_bit_cast(unsigned, lo);
  unsigned r2 = u2 + 0x7FFFu + ((u2 >> 16) & 1u);
  ls = (short)(r2 >> 16);
}

// ============================ conv1: 9x9 s1 + ReLU ==========================
__global__ __launch_bounds__(320) void conv1_k(
    const float* __restrict__ inp, const float* __restrict__ W1,
    const float* __restrict__ b1, short* __restrict__ xhi,
    short* __restrict__ xlo) {
  __shared__ __align__(16) float img[784];
  __shared__ float wl[81 * 34];
  const int blk = blockIdx.x;
  const int b = blk >> 3;
  const int cbase = (blk & 7) * 32;
  const int t = threadIdx.x;

  const float4* src = (const float4*)(inp + b * 784);
  for (int idx = t; idx < 196; idx += 320) ((float4*)img)[idx] = src[idx];
  for (int idx = t; idx < 2592; idx += 320) {
    int c = idx / 81, tap = idx - c * 81;
    wl[tap * 34 + c] = W1[(cbase + c) * 81 + tap];
  }
  __syncthreads();

  const int oy = t >> 4;
  const int ct = t & 15;
  const int c0 = cbase + ct * 2;
  const float bias0 = b1[c0], bias1 = b1[c0 + 1];
  float acc0[20], acc1[20];
#pragma unroll
  for (int ox = 0; ox < 20; ox++) { acc0[ox] = bias0; acc1[ox] = bias1; }

#pragma unroll 1
  for (int i = 0; i < 9; i++) {
    float wr0[9], wr1[9];
#pragma unroll
    for (int j = 0; j < 9; j++) {
      float2 wv = *(const float2*)&wl[(i * 9 + j) * 34 + ct * 2];
      wr0[j] = wv.x; wr1[j] = wv.y;
    }
    float xr[28];
    const float4* rp = (const float4*)&img[(oy + i) * 28];
#pragma unroll
    for (int k = 0; k < 7; k++) {
      float4 v = rp[k];
      xr[4 * k] = v.x; xr[4 * k + 1] = v.y; xr[4 * k + 2] = v.z; xr[4 * k + 3] = v.w;
    }
#pragma unroll
    for (int j = 0; j < 9; j++)
#pragma unroll
      for (int ox = 0; ox < 20; ox++) {
        acc0[ox] = fmaf(xr[ox + j], wr0[j], acc0[ox]);
        acc1[ox] = fmaf(xr[ox + j], wr1[j], acc1[ox]);
      }
  }
  const long pbase = (long)(b * 400 + oy * 20) * 256 + c0;
#pragma unroll
  for (int ox = 0; ox < 20; ox++) {
    float v0 = fmaxf(acc0[ox], 0.f), v1 = fmaxf(acc1[ox], 0.f);
    short h0, l0, h1, l1;
    bf16split(v0, h0, l0);
    bf16split(v1, h1, l1);
    long a = pbase + (long)ox * 256;
    *(short2*)&xhi[a] = make_short2(h0, h1);
    *(short2*)&xlo[a] = make_short2(l0, l1);
  }
}

// ======= W2 transform: fp32 [oc][ic][81] -> bf16 hi/lo, 88-tap padded =======
// out layout: [tap(88)][icg(32)][oc(256)][ics(8)]; taps 81..87 zero.
__global__ __launch_bounds__(256) void wtrans_k(
    const float* __restrict__ W2, short* __restrict__ whi,
    short* __restrict__ wlo) {
  const int idx = blockIdx.x * 256 + threadIdx.x;  // < 5767168
  const int ics = idx & 7;
  const int oc = (idx >> 3) & 255;
  const int icg = (idx >> 11) & 31;
  const int tap = idx >> 16;
  short h = 0, l = 0;
  if (tap < 81) {
    const int ic = icg * 8 + ics;
    bf16split(W2[(oc * 256 + ic) * 81 + tap], h, l);
  }
  whi[idx] = h;
  wlo[idx] = l;
}

// ================= conv2: MFMA bf16-split implicit GEMM =====================
// grid 512: ks = blk&7 == XCD, mb = blk>>3 (4 images). Block M144 x N256;
// 4 waves x (9m,4n). Merged tri-term kst loop, ping-pong B register sets
// (no copy movs), pointer-bump weight addressing with imm per-load offsets.
#define CONV2_BODY(KST, CH, CL, NH, NL)                                      \
  {                                                                          \
    _Pragma("unroll")                                                        \
    for (int nt = 0; nt < 4; nt++) {                                         \
      NH[nt] = *(const bf16x8*)(pWn + nt * 128);                             \
      NL[nt] = *(const bf16x8*)(pLn + nt * 128);                             \
    }                                                                        \
    pWn += KSTSTRIDE; pLn += KSTSTRIDE;                                      \
    const int tap = (KST) * 4 + q;                                           \
    const int i = tap / 9, j = tap - i * 9;                                  \
    const int aoff = (j & 1) * SL_PAR + i * SL_IY + (j >> 1) * 8;            \
    _Pragma("unroll")                                                        \
    for (int bb = 0; bb < 3; bb++) {                                         \
      bf16x8 ah[3], al[3];                                                   \
      _Pragma("unroll")                                                      \
      for (int m3 = 0; m3 < 3; m3++) {                                       \
        ah[m3] = *(const bf16x8*)&slabH[aoff + combo[bb * 3 + m3]];          \
        al[m3] = *(const bf16x8*)&slabL[aoff + combo[bb * 3 + m3]];          \
      }                                                                      \
      _Pragma("unroll")                                                      \
      for (int nt = 0; nt < 4; nt++)                                         \
        _Pragma("unroll")                                                    \
        for (int m3 = 0; m3 < 3; m3++)                                       \
          acc[bb * 3 + m3][nt] = __builtin_amdgcn_mfma_f32_16x16x32_bf16(    \
              ah[m3], CH[nt], acc[bb * 3 + m3][nt], 0, 0, 0);                \
      _Pragma("unroll")                                                      \
      for (int nt = 0; nt < 4; nt++)                                         \
        _Pragma("unroll")                                                    \
        for (int m3 = 0; m3 < 3; m3++)                                       \
          acc[bb * 3 + m3][nt] = __builtin_amdgcn_mfma_f32_16x16x32_bf16(    \
              ah[m3], CL[nt], acc[bb * 3 + m3][nt], 0, 0, 0);                \
      _Pragma("unroll")                                                      \
      for (int nt = 0; nt < 4; nt++)                                         \
        _Pragma("unroll")                                                    \
        for (int m3 = 0; m3 < 3; m3++)                                       \
          acc[bb * 3 + m3][nt] = __builtin_amdgcn_mfma_f32_16x16x32_bf16(    \
              al[m3], CH[nt], acc[bb * 3 + m3][nt], 0, 0, 0);                \
    }                                                                        \
  }

__global__ __launch_bounds__(256, 2) void conv2_k(
    const short* __restrict__ xhi, const short* __restrict__ xlo,
    const short* __restrict__ whi, const short* __restrict__ wlo,
    float* __restrict__ y2) {
  __shared__ __align__(16) short slabH[SL_TOT];   // 28.3 KB
  __shared__ __align__(16) short slabL[SL_TOT];   // 28.3 KB

  const int blk = blockIdx.x;
  const int ks = blk & 7;
  const int mb = blk >> 3;
  const int b0 = mb * 4;
  const int t = threadIdx.x;
  const int lane = t & 63;
  const int q = lane >> 4;
  const int ln16 = lane & 15;
  const int wv = t >> 6;

  int combo[9];
#pragma unroll
  for (int mt = 0; mt < 9; mt++) {
    int row = mt * 16 + ln16;
    int im = row / 36;
    int pos = row - im * 36;
    int oy = pos / 6, ox = pos - oy * 6;
    combo[mt] = im * SL_IMG + oy * (2 * SL_IY) + ox * 8;
  }

  floatx4 acc[9][4];
#pragma unroll
  for (int mt = 0; mt < 9; mt++)
#pragma unroll
    for (int nt = 0; nt < 4; nt++) acc[mt][nt] = (floatx4)0.f;

#pragma unroll 1
  for (int icg = 0; icg < 4; icg++) {
    const int icgG = ks * 4 + icg;
    const long icoff = (long)icgG * 8;
    const long wb0 = ((long)icgG * 256 + wv * 64 + ln16) * 8 + (long)q * TAPSTRIDE;

    // stage A_hi + A_lo slabs (nontemporal: spare L2 for weights)
    __syncthreads();
    for (int idx = t; idx < 1600; idx += 256) {
      int im = idx / 400, p = idx - im * 400;
      int iy = p / 20, ix = p - iy * 20;
      int dst = (ix & 1) * SL_PAR + im * SL_IMG + iy * SL_IY + (ix >> 1) * 8;
      const long src = ((long)(b0 + im) * 400 + p) * 256 + icoff;
      uintx4 vh = __builtin_nontemporal_load((const uintx4*)&xhi[src]);
      uintx4 vl = __builtin_nontemporal_load((const uintx4*)&xlo[src]);
      *(uintx4*)&slabH[dst] = vh;
      *(uintx4*)&slabL[dst] = vl;
    }
    __syncthreads();

    const short* pWn = whi + wb0;      // marching prefetch pointers
    const short* pLn = wlo + wb0;
    bf16x8 c0h[4], c0l[4], c1h[4], c1l[4];
#pragma unroll
    for (int nt = 0; nt < 4; nt++) {   // preload kst 0
      c0h[nt] = *(const bf16x8*)(pWn + nt * 128);
      c0l[nt] = *(const bf16x8*)(pLn + nt * 128);
    }
    pWn += KSTSTRIDE; pLn += KSTSTRIDE;

#pragma unroll 1
    for (int k2 = 0; k2 < 10; k2++) {
      CONV2_BODY(2 * k2,     c0h, c0l, c1h, c1l)   // prefetch -> c1
      CONV2_BODY(2 * k2 + 1, c1h, c1l, c0h, c0l)   // prefetch -> c0
    }
    // tail kst = 20 (prefetch target is zero-pad taps 84..87, harmless)
    CONV2_BODY(20, c0h, c0l, c1h, c1l)
  }

  // epilogue: C/D layout col(n)=lane&15, row(m)=q*4+r; atomic over 8 ic-splits
#pragma unroll
  for (int mt = 0; mt < 9; mt++)
#pragma unroll
    for (int nt = 0; nt < 4; nt++) {
      int oc = wv * 64 + nt * 16 + ln16;
      int rowb = mb * 144 + mt * 16 + q * 4;
#pragma unroll
      for (int r = 0; r < 4; r++)
        atomicAdd(&y2[(long)(rowb + r) * 256 + oc], acc[mt][nt][r]);
    }
}

// ================= primary caps squash + predictions + routing ==============
// grid 8192, 256 thr; g = blk&31 keeps Wcaps slice L2-hot per XCD.
__global__ __launch_bounds__(256) void caps_k(
    const float* __restrict__ y2, const float* __restrict__ b2,
    const float* __restrict__ Wcaps, const float* __restrict__ b_route,
    float* __restrict__ vpart) {
  __shared__ float u[288];
  __shared__ float usc[36];
  __shared__ float up[5760];
  __shared__ float bl[360];
  __shared__ float cl[360];
  __shared__ float sv[160];
  __shared__ float vv[160];
  __shared__ float scale[10];
  const int blk = blockIdx.x;
  const int g = blk & 31, b = blk >> 5;
  const int t = threadIdx.x;

  for (int idx = t; idx < 288; idx += 256) {
    int s = idx >> 3, d = idx & 7;
    u[idx] = y2[((long)b * 36 + s) * 256 + g * 8 + d] + b2[g * 8 + d];
  }
  for (int idx = t; idx < 360; idx += 256) bl[idx] = b_route[g * 360 + idx];
  __syncthreads();
  if (t < 36) {
    float l2 = 0.f;
#pragma unroll
    for (int d = 0; d < 8; d++) { float v = u[t * 8 + d]; l2 = fmaf(v, v, l2); }
    float l = sqrtf(l2);
    usc[t] = (l2 / (1.f + l2)) / (l + 1e-8f);
  }
  __syncthreads();
  for (int idx = t; idx < 288; idx += 256) u[idx] *= usc[idx >> 3];
  __syncthreads();
  for (int idx = t; idx < 5760; idx += 256) {
    int s = idx / 160, k = idx - s * 160;
    const float* wp = Wcaps + (g * 36 + s) * 8 * 160 + k;
    float a = 0.f;
#pragma unroll
    for (int d = 0; d < 8; d++) a = fmaf(u[s * 8 + d], wp[d * 160], a);
    up[idx] = a;
  }
  __syncthreads();

  for (int r = 0; r < 3; r++) {
    if (t < 36) {
      float m = bl[t * 10];
#pragma unroll
      for (int oc = 1; oc < 10; oc++) m = fmaxf(m, bl[t * 10 + oc]);
      float e[10]; float sum = 0.f;
#pragma unroll
      for (int oc = 0; oc < 10; oc++) { e[oc] = expf(bl[t * 10 + oc] - m); sum += e[oc]; }
      float inv = 1.f / sum;
#pragma unroll
      for (int oc = 0; oc < 10; oc++) cl[t * 10 + oc] = e[oc] * inv;
    }
    __syncthreads();
    if (t < 160) {
      const int oc = t >> 4;
      float a = 0.f;
#pragma unroll 1
      for (int s = 0; s < 36; s++) a = fmaf(cl[s * 10 + oc], up[s * 160 + t], a);
      sv[t] = a;
    }
    __syncthreads();
    if (t < 10) {
      float l2 = 0.f;
#pragma unroll
      for (int od = 0; od < 16; od++) { float v = sv[t * 16 + od]; l2 = fmaf(v, v, l2); }
      scale[t] = (l2 / (1.f + l2)) / (sqrtf(l2) + 1e-8f);
    }
    __syncthreads();
    if (t < 160) vv[t] = sv[t] * scale[t >> 4];
    __syncthreads();
    if (r < 2) {
      for (int idx = t; idx < 360; idx += 256) {
        int s = idx / 10, oc = idx - s * 10;
        float a = 0.f;
#pragma unroll
        for (int od = 0; od < 16; od++)
          a = fmaf(up[s * 160 + oc * 16 + od], vv[oc * 16 + od], a);
        bl[idx] += a;
      }
      __syncthreads();
    }
  }
  if (t < 160) vpart[(b * 32 + g) * 160 + t] = vv[t];
}

// ================== final: sum over groups + probs ==========================
__global__ __launch_bounds__(192) void final_k(
    const float* __restrict__ vpart, float* __restrict__ out) {
  __shared__ float v[160];
  const int b = blockIdx.x, t = threadIdx.x;
  if (t < 160) {
    float a = 0.f;
#pragma unroll 4
    for (int g = 0; g < 32; g++) a += vpart[(b * 32 + g) * 160 + t];
    v[t] = a;
    out[b * 160 + t] = a;
  }
  __syncthreads();
  if (t < 10) {
    float l2 = 0.f;
#pragma unroll
    for (int od = 0; od < 16; od++) { float x = v[t * 16 + od]; l2 = fmaf(x, x, l2); }
    out[40960 + b * 10 + t] = sqrtf(l2);
  }
}

// ===========================================================================
extern "C" void kernel_launch(void* const* d_in, const int* in_sizes, int n_in,
                              void* d_out, int out_size, void* d_ws, size_t ws_size,
                              hipStream_t stream) {
  const float* inp     = (const float*)d_in[0];
  const float* W1      = (const float*)d_in[1];
  const float* b1      = (const float*)d_in[2];
  const float* W2      = (const float*)d_in[3];
  const float* b2      = (const float*)d_in[4];
  const float* Wcaps   = (const float*)d_in[5];
  const float* b_route = (const float*)d_in[6];
  float* out = (float*)d_out;
  char* ws = (char*)d_ws;

  short* xhi = (short*)(ws + XHI_OFF);
  short* xlo = (short*)(ws + XLO_OFF);
  short* whi = (short*)(ws + WHI_OFF);
  short* wlo = (short*)(ws + WLO_OFF);
  float* y2  = (float*)(ws + Y2_OFF);
  float* vp  = (float*)(ws + VP_OFF);

  (void)hipMemsetAsync(y2, 0, Y2_BYTES, stream);
  conv1_k <<<2048, 320, 0, stream>>>(inp, W1, b1, xhi, xlo);
  wtrans_k<<<22528, 256, 0, stream>>>(W2, whi, wlo);
  conv2_k <<<512, 256, 0, stream>>>(xhi, xlo, whi, wlo, y2);
  caps_k  <<<8192, 256, 0, stream>>>(y2, b2, Wcaps, b_route, vp);
  final_k <<<256, 192, 0, stream>>>(vp, out);
}

// Round 12
// 561.444 us; speedup vs baseline: 1.0982x; 1.0657x over previous
//
#include <hip/hip_runtime.h>
#include <math.h>

// ---------------------------------------------------------------------------
// CapsNet forward on MI355X.
// R12: conv2 reverted to R7 structure (best measured: 297us; R11 ping-pong
//      spilled - VGPR 128, WRITE 117MB scratch). wtrans rewritten as
//      coalesced LDS transpose (old version: 324B-stride reads = 32x line
//      overfetch on 21MB -> est 60-100us of hidden tail time).
// ---------------------------------------------------------------------------

typedef float floatx4 __attribute__((ext_vector_type(4)));
typedef __bf16 bf16x8 __attribute__((ext_vector_type(8)));
typedef unsigned uintx4 __attribute__((ext_vector_type(4)));

#define XHI_OFF 0u
#define XLO_OFF 52428800u
#define WHI_OFF 104857600u          // 88*32*256*8 shorts = 11534336 B
#define WLO_OFF 116391936u
#define Y2_OFF  127926272u
#define VP_OFF  137363456u
#define Y2_BYTES 9437184u

// slab geometry (shorts): iy stride 88, img stride 1760, parity offset 7072
#define SL_IY   88
#define SL_IMG  1760
#define SL_PAR  7072
#define SL_TOT  14144

#define TAPSTRIDE 65536            // shorts per tap in w layout

__device__ __forceinline__ void bf16split(float v, short& hs, short& ls) {
  unsigned u = __builtin_bit_cast(unsigned, v);
  unsigned r = (u + 0x7FFFu + ((u >> 16) & 1u)) & 0xFFFF0000u;
  hs = (short)(r >> 16);
  float lo = v - __builtin_bit_cast(float, r);
  unsigned u2 = __builtin_bit_cast(unsigned, lo);
  unsigned r2 = u2 + 0x7FFFu + ((u2 >> 16) & 1u);
  ls = (short)(r2 >> 16);
}

// ============================ conv1: 9x9 s1 + ReLU ==========================
__global__ __launch_bounds__(320) void conv1_k(
    const float* __restrict__ inp, const float* __restrict__ W1,
    const float* __restrict__ b1, short* __restrict__ xhi,
    short* __restrict__ xlo) {
  __shared__ __align__(16) float img[784];
  __shared__ float wl[81 * 34];
  const int blk = blockIdx.x;
  const int b = blk >> 3;
  const int cbase = (blk & 7) * 32;
  const int t = threadIdx.x;

  const float4* src = (const float4*)(inp + b * 784);
  for (int idx = t; idx < 196; idx += 320) ((float4*)img)[idx] = src[idx];
  for (int idx = t; idx < 2592; idx += 320) {
    int c = idx / 81, tap = idx - c * 81;
    wl[tap * 34 + c] = W1[(cbase + c) * 81 + tap];
  }
  __syncthreads();

  const int oy = t >> 4;
  const int ct = t & 15;
  const int c0 = cbase + ct * 2;
  const float bias0 = b1[c0], bias1 = b1[c0 + 1];
  float acc0[20], acc1[20];
#pragma unroll
  for (int ox = 0; ox < 20; ox++) { acc0[ox] = bias0; acc1[ox] = bias1; }

#pragma unroll 1
  for (int i = 0; i < 9; i++) {
    float wr0[9], wr1[9];
#pragma unroll
    for (int j = 0; j < 9; j++) {
      float2 wv = *(const float2*)&wl[(i * 9 + j) * 34 + ct * 2];
      wr0[j] = wv.x; wr1[j] = wv.y;
    }
    float xr[28];
    const float4* rp = (const float4*)&img[(oy + i) * 28];
#pragma unroll
    for (int k = 0; k < 7; k++) {
      float4 v = rp[k];
      xr[4 * k] = v.x; xr[4 * k + 1] = v.y; xr[4 * k + 2] = v.z; xr[4 * k + 3] = v.w;
    }
#pragma unroll
    for (int j = 0; j < 9; j++)
#pragma unroll
      for (int ox = 0; ox < 20; ox++) {
        acc0[ox] = fmaf(xr[ox + j], wr0[j], acc0[ox]);
        acc1[ox] = fmaf(xr[ox + j], wr1[j], acc1[ox]);
      }
  }
  const long pbase = (long)(b * 400 + oy * 20) * 256 + c0;
#pragma unroll
  for (int ox = 0; ox < 20; ox++) {
    float v0 = fmaxf(acc0[ox], 0.f), v1 = fmaxf(acc1[ox], 0.f);
    short h0, l0, h1, l1;
    bf16split(v0, h0, l0);
    bf16split(v1, h1, l1);
    long a = pbase + (long)ox * 256;
    *(short2*)&xhi[a] = make_short2(h0, h1);
    *(short2*)&xlo[a] = make_short2(l0, l1);
  }
}

// ======= W2 transform (coalesced LDS transpose) =============================
// 256 blocks: icg = blk&31, ocg = blk>>5 (32 oc each). Reads 32 contiguous
// 648-float chunks (coalesced); LDS stride 258 breaks the tap*512B bank
// collision; out writes are 128B/wave coalesced rows. Taps 81..87 zeroed.
__global__ __launch_bounds__(256) void wtrans_k(
    const float* __restrict__ W2, short* __restrict__ whi,
    short* __restrict__ wlo) {
  __shared__ short lh[81 * 258];
  __shared__ short ll[81 * 258];
  const int blk = blockIdx.x;
  const int icg = blk & 31, ocg = blk >> 5;
  const int t = threadIdx.x;

  for (int idx = t; idx < 20736; idx += 256) {
    int c = idx / 648, r = idx - c * 648;      // c = oc_local, r = ics*81+tap
    int ics = r / 81, tap = r - ics * 81;
    float v = W2[(long)(ocg * 32 + c) * 20736 + icg * 648 + r];
    short h, l;
    bf16split(v, h, l);
    lh[tap * 258 + c * 8 + ics] = h;
    ll[tap * 258 + c * 8 + ics] = l;
  }
  __syncthreads();
  const long obase = (long)icg * 2048 + ocg * 256 + t;
#pragma unroll 1
  for (int tap = 0; tap < 88; tap++) {
    short h = 0, l = 0;
    if (tap < 81) { h = lh[tap * 258 + t]; l = ll[tap * 258 + t]; }
    whi[obase + (long)tap * TAPSTRIDE] = h;
    wlo[obase + (long)tap * TAPSTRIDE] = l;
  }
}

// ================= conv2: MFMA bf16-split implicit GEMM =====================
// grid 512: ks = blk&7 == XCD, mb = blk>>3 (4 images). Block M144 x N256;
// 4 waves x (9m,4n). Separate HI/LO phases (R7 structure, best measured);
// B-hi 1-step reg prefetch, B-lo in-iteration; A from repadded LDS slab,
// 3-mt batches; nontemporal x staging.
__global__ __launch_bounds__(256, 2) void conv2_k(
    const short* __restrict__ xhi, const short* __restrict__ xlo,
    const short* __restrict__ whi, const short* __restrict__ wlo,
    float* __restrict__ y2) {
  __shared__ __align__(16) short slabA[SL_TOT];   // 28.3 KB

  const int blk = blockIdx.x;
  const int ks = blk & 7;
  const int mb = blk >> 3;
  const int b0 = mb * 4;
  const int t = threadIdx.x;
  const int lane = t & 63;
  const int q = lane >> 4;
  const int ln16 = lane & 15;
  const int wv = t >> 6;

  int combo[9];
#pragma unroll
  for (int mt = 0; mt < 9; mt++) {
    int row = mt * 16 + ln16;
    int im = row / 36;
    int pos = row - im * 36;
    int oy = pos / 6, ox = pos - oy * 6;
    combo[mt] = im * SL_IMG + oy * (2 * SL_IY) + ox * 8;
  }

  floatx4 acc[9][4];
#pragma unroll
  for (int mt = 0; mt < 9; mt++)
#pragma unroll
    for (int nt = 0; nt < 4; nt++) acc[mt][nt] = (floatx4)0.f;

#pragma unroll 1
  for (int icg = 0; icg < 4; icg++) {
    const int icgG = ks * 4 + icg;
    const long icoff = (long)icgG * 8;
    const long wb0 = ((long)icgG * 256 + wv * 64 + ln16) * 8 + (long)q * TAPSTRIDE;

    // ---------------- HI phase: A_hi * (B_hi + B_lo) ----------------
    __syncthreads();
    for (int idx = t; idx < 1600; idx += 256) {
      int im = idx / 400, p = idx - im * 400;
      int iy = p / 20, ix = p - iy * 20;
      int dst = (ix & 1) * SL_PAR + im * SL_IMG + iy * SL_IY + (ix >> 1) * 8;
      const long src = ((long)(b0 + im) * 400 + p) * 256 + icoff;
      uintx4 vh = __builtin_nontemporal_load((const uintx4*)&xhi[src]);
      *(uintx4*)&slabA[dst] = vh;
    }
    __syncthreads();

    {
      bf16x8 cbh[4];
#pragma unroll
      for (int nt = 0; nt < 4; nt++) cbh[nt] = *(const bf16x8*)&whi[wb0 + nt * 128];
#pragma unroll 1
      for (int kst = 0; kst < 21; kst++) {
        const int t0n = (kst < 20) ? (kst + 1) * 4 : 80;
        bf16x8 nbh[4], cbl[4];
#pragma unroll
        for (int nt = 0; nt < 4; nt++) {
          nbh[nt] = *(const bf16x8*)&whi[wb0 + (long)t0n * TAPSTRIDE + nt * 128];
          cbl[nt] = *(const bf16x8*)&wlo[wb0 + (long)(kst * 4) * TAPSTRIDE + nt * 128];
        }
        const int tap = kst * 4 + q;
        const int i = tap / 9, j = tap - i * 9;
        const int aoff = (j & 1) * SL_PAR + i * SL_IY + (j >> 1) * 8;
#pragma unroll
        for (int bb = 0; bb < 3; bb++) {
          bf16x8 av[3];
#pragma unroll
          for (int m3 = 0; m3 < 3; m3++)
            av[m3] = *(const bf16x8*)&slabA[aoff + combo[bb * 3 + m3]];
#pragma unroll
          for (int nt = 0; nt < 4; nt++)
#pragma unroll
            for (int m3 = 0; m3 < 3; m3++)
              acc[bb * 3 + m3][nt] = __builtin_amdgcn_mfma_f32_16x16x32_bf16(
                  av[m3], cbh[nt], acc[bb * 3 + m3][nt], 0, 0, 0);
#pragma unroll
          for (int nt = 0; nt < 4; nt++)
#pragma unroll
            for (int m3 = 0; m3 < 3; m3++)
              acc[bb * 3 + m3][nt] = __builtin_amdgcn_mfma_f32_16x16x32_bf16(
                  av[m3], cbl[nt], acc[bb * 3 + m3][nt], 0, 0, 0);
        }
#pragma unroll
        for (int nt = 0; nt < 4; nt++) cbh[nt] = nbh[nt];
      }
    }

    // ---------------- LO phase: A_lo * B_hi ----------------
    __syncthreads();
    for (int idx = t; idx < 1600; idx += 256) {
      int im = idx / 400, p = idx - im * 400;
      int iy = p / 20, ix = p - iy * 20;
      int dst = (ix & 1) * SL_PAR + im * SL_IMG + iy * SL_IY + (ix >> 1) * 8;
      const long src = ((long)(b0 + im) * 400 + p) * 256 + icoff;
      uintx4 vl = __builtin_nontemporal_load((const uintx4*)&xlo[src]);
      *(uintx4*)&slabA[dst] = vl;
    }
    __syncthreads();

    {
      bf16x8 cbh[4];
#pragma unroll
      for (int nt = 0; nt < 4; nt++) cbh[nt] = *(const bf16x8*)&whi[wb0 + nt * 128];
#pragma unroll 1
      for (int kst = 0; kst < 21; kst++) {
        const int t0n = (kst < 20) ? (kst + 1) * 4 : 80;
        bf16x8 nbh[4];
#pragma unroll
        for (int nt = 0; nt < 4; nt++)
          nbh[nt] = *(const bf16x8*)&whi[wb0 + (long)t0n * TAPSTRIDE + nt * 128];
        const int tap = kst * 4 + q;
        const int i = tap / 9, j = tap - i * 9;
        const int aoff = (j & 1) * SL_PAR + i * SL_IY + (j >> 1) * 8;
#pragma unroll
        for (int bb = 0; bb < 3; bb++) {
          bf16x8 av[3];
#pragma unroll
          for (int m3 = 0; m3 < 3; m3++)
            av[m3] = *(const bf16x8*)&slabA[aoff + combo[bb * 3 + m3]];
#pragma unroll
          for (int nt = 0; nt < 4; nt++)
#pragma unroll
            for (int m3 = 0; m3 < 3; m3++)
              acc[bb * 3 + m3][nt] = __builtin_amdgcn_mfma_f32_16x16x32_bf16(
                  av[m3], cbh[nt], acc[bb * 3 + m3][nt], 0, 0, 0);
        }
#pragma unroll
        for (int nt = 0; nt < 4; nt++) cbh[nt] = nbh[nt];
      }
    }
  }

  // epilogue: C/D layout col(n)=lane&15, row(m)=q*4+r; atomic over 8 ic-splits
#pragma unroll
  for (int mt = 0; mt < 9; mt++)
#pragma unroll
    for (int nt = 0; nt < 4; nt++) {
      int oc = wv * 64 + nt * 16 + ln16;
      int rowb = mb * 144 + mt * 16 + q * 4;
#pragma unroll
      for (int r = 0; r < 4; r++)
        atomicAdd(&y2[(long)(rowb + r) * 256 + oc], acc[mt][nt][r]);
    }
}

// ================= primary caps squash + predictions + routing ==============
// grid 8192, 256 thr; g = blk&31 keeps Wcaps slice L2-hot per XCD.
__global__ __launch_bounds__(256) void caps_k(
    const float* __restrict__ y2, const float* __restrict__ b2,
    const float* __restrict__ Wcaps, const float* __restrict__ b_route,
    float* __restrict__ vpart) {
  __shared__ float u[288];
  __shared__ float usc[36];
  __shared__ float up[5760];
  __shared__ float bl[360];
  __shared__ float cl[360];
  __shared__ float sv[160];
  __shared__ float vv[160];
  __shared__ float scale[10];
  const int blk = blockIdx.x;
  const int g = blk & 31, b = blk >> 5;
  const int t = threadIdx.x;

  for (int idx = t; idx < 288; idx += 256) {
    int s = idx >> 3, d = idx & 7;
    u[idx] = y2[((long)b * 36 + s) * 256 + g * 8 + d] + b2[g * 8 + d];
  }
  for (int idx = t; idx < 360; idx += 256) bl[idx] = b_route[g * 360 + idx];
  __syncthreads();
  if (t < 36) {
    float l2 = 0.f;
#pragma unroll
    for (int d = 0; d < 8; d++) { float v = u[t * 8 + d]; l2 = fmaf(v, v, l2); }
    float l = sqrtf(l2);
    usc[t] = (l2 / (1.f + l2)) / (l + 1e-8f);
  }
  __syncthreads();
  for (int idx = t; idx < 288; idx += 256) u[idx] *= usc[idx >> 3];
  __syncthreads();
  for (int idx = t; idx < 5760; idx += 256) {
    int s = idx / 160, k = idx - s * 160;
    const float* wp = Wcaps + (g * 36 + s) * 8 * 160 + k;
    float a = 0.f;
#pragma unroll
    for (int d = 0; d < 8; d++) a = fmaf(u[s * 8 + d], wp[d * 160], a);
    up[idx] = a;
  }
  __syncthreads();

  for (int r = 0; r < 3; r++) {
    if (t < 36) {
      float m = bl[t * 10];
#pragma unroll
      for (int oc = 1; oc < 10; oc++) m = fmaxf(m, bl[t * 10 + oc]);
      float e[10]; float sum = 0.f;
#pragma unroll
      for (int oc = 0; oc < 10; oc++) { e[oc] = expf(bl[t * 10 + oc] - m); sum += e[oc]; }
      float inv = 1.f / sum;
#pragma unroll
      for (int oc = 0; oc < 10; oc++) cl[t * 10 + oc] = e[oc] * inv;
    }
    __syncthreads();
    if (t < 160) {
      const int oc = t >> 4;
      float a = 0.f;
#pragma unroll 1
      for (int s = 0; s < 36; s++) a = fmaf(cl[s * 10 + oc], up[s * 160 + t], a);
      sv[t] = a;
    }
    __syncthreads();
    if (t < 10) {
      float l2 = 0.f;
#pragma unroll
      for (int od = 0; od < 16; od++) { float v = sv[t * 16 + od]; l2 = fmaf(v, v, l2); }
      scale[t] = (l2 / (1.f + l2)) / (sqrtf(l2) + 1e-8f);
    }
    __syncthreads();
    if (t < 160) vv[t] = sv[t] * scale[t >> 4];
    __syncthreads();
    if (r < 2) {
      for (int idx = t; idx < 360; idx += 256) {
        int s = idx / 10, oc = idx - s * 10;
        float a = 0.f;
#pragma unroll
        for (int od = 0; od < 16; od++)
          a = fmaf(up[s * 160 + oc * 16 + od], vv[oc * 16 + od], a);
        bl[idx] += a;
      }
      __syncthreads();
    }
  }
  if (t < 160) vpart[(b * 32 + g) * 160 + t] = vv[t];
}

// ================== final: sum over groups + probs ==========================
__global__ __launch_bounds__(192) void final_k(
    const float* __restrict__ vpart, float* __restrict__ out) {
  __shared__ float v[160];
  const int b = blockIdx.x, t = threadIdx.x;
  if (t < 160) {
    float a = 0.f;
#pragma unroll 4
    for (int g = 0; g < 32; g++) a += vpart[(b * 32 + g) * 160 + t];
    v[t] = a;
    out[b * 160 + t] = a;
  }
  __syncthreads();
  if (t < 10) {
    float l2 = 0.f;
#pragma unroll
    for (int od = 0; od < 16; od++) { float x = v[t * 16 + od]; l2 = fmaf(x, x, l2); }
    out[40960 + b * 10 + t] = sqrtf(l2);
  }
}

// ===========================================================================
extern "C" void kernel_launch(void* const* d_in, const int* in_sizes, int n_in,
                              void* d_out, int out_size, void* d_ws, size_t ws_size,
                              hipStream_t stream) {
  const float* inp     = (const float*)d_in[0];
  const float* W1      = (const float*)d_in[1];
  const float* b1      = (const float*)d_in[2];
  const float* W2      = (const float*)d_in[3];
  const float* b2      = (const float*)d_in[4];
  const float* Wcaps   = (const float*)d_in[5];
  const float* b_route = (const float*)d_in[6];
  float* out = (float*)d_out;
  char* ws = (char*)d_ws;

  short* xhi = (short*)(ws + XHI_OFF);
  short* xlo = (short*)(ws + XLO_OFF);
  short* whi = (short*)(ws + WHI_OFF);
  short* wlo = (short*)(ws + WLO_OFF);
  float* y2  = (float*)(ws + Y2_OFF);
  float* vp  = (float*)(ws + VP_OFF);

  (void)hipMemsetAsync(y2, 0, Y2_BYTES, stream);
  conv1_k <<<2048, 320, 0, stream>>>(inp, W1, b1, xhi, xlo);
  wtrans_k<<<256, 256, 0, stream>>>(W2, whi, wlo);
  conv2_k <<<512, 256, 0, stream>>>(xhi, xlo, whi, wlo, y2);
  caps_k  <<<8192, 256, 0, stream>>>(y2, b2, Wcaps, b_route, vp);
  final_k <<<256, 192, 0, stream>>>(vp, out);
}